// Round 16
// baseline (151.359 us; speedup 1.0000x reference)
//
#include <hip/hip_runtime.h>
#include <hip/hip_bf16.h>
#include <math.h>

// ---------------------------------------------------------------------------
// CrossCausalAttentionBlock on MI355X (gfx950)
// B=8, T=1024 (V=4 blocks of 256), C=512, NH=8, hd=64
// R16: T4 counted-vmcnt ported to attention (3-deep K/V rotation, VM_FENCE(2)
//      per tile instead of full-drain __syncthreads). GEMMs unchanged (R15).
// ---------------------------------------------------------------------------

typedef __bf16 bf16;
typedef __bf16 bf16x8 __attribute__((ext_vector_type(8)));
typedef __bf16 bf16x4 __attribute__((ext_vector_type(4)));
typedef float  f32x4  __attribute__((ext_vector_type(4)));

__device__ __forceinline__ void gload_lds16(const void* g, void* l) {
  __builtin_amdgcn_global_load_lds(
      (__attribute__((address_space(1))) void*)(g),
      (__attribute__((address_space(3))) void*)(l), 16, 0, 0);
}

// counted-vmcnt fence: wait until <= N vmem ops outstanding (oldest retire
// first), then raw barrier. After this, ALL waves' stage-k LDS writes have
// landed while newer stages stay in flight.
#define VM_FENCE(N)                                              \
  do {                                                           \
    asm volatile("s_waitcnt vmcnt(" #N ")" ::: "memory");        \
    __builtin_amdgcn_sched_barrier(0);                           \
    __builtin_amdgcn_s_barrier();                                \
    __builtin_amdgcn_sched_barrier(0);                           \
  } while (0)

// ---------------------------------------------------------------------------
// Kernel 1: prep. Blocks 0..767: weight convert 64x64 tiles. 768..1535:
// gather+LN1 h-pair blocks (register-resident, vector loads/stores).
// ---------------------------------------------------------------------------
__global__ __launch_bounds__(256)
void prep_k(const float* __restrict__ Wq, const float* __restrict__ Wkv,
            const float* __restrict__ Wo, const float* __restrict__ Wfc,
            const float* __restrict__ Wpr,
            bf16* __restrict__ WqT, bf16* __restrict__ WkvT,
            bf16* __restrict__ WoT, bf16* __restrict__ WfcT,
            bf16* __restrict__ WprT,
            const float* __restrict__ xi, const float* __restrict__ xj,
            const float* __restrict__ xc,
            const float* __restrict__ g, const float* __restrict__ bb,
            bf16* __restrict__ qs, bf16* __restrict__ kvs,
            bf16* __restrict__ csb)
{
  __shared__ float tile[64 * 65]; // 16.6 KB (wconv half)
  __shared__ float red[4][64];    // 1 KB (LN half)
  const int t = blockIdx.x;
  const int tid = threadIdx.x;
  if (t < 768) { // ---- weight transpose-convert, 64x64 tiles
    const float* W; bf16* Wt; int K, N, nx, tl;
    if (t < 64)        { W = Wq;  Wt = WqT;  K = 512;  N = 512;  nx = 8;  tl = t; }
    else if (t < 192)  { W = Wkv; Wt = WkvT; K = 512;  N = 1024; nx = 16; tl = t - 64; }
    else if (t < 256)  { W = Wo;  Wt = WoT;  K = 512;  N = 512;  nx = 8;  tl = t - 192; }
    else if (t < 512)  { W = Wfc; Wt = WfcT; K = 512;  N = 2048; nx = 32; tl = t - 256; }
    else               { W = Wpr; Wt = WprT; K = 2048; N = 512;  nx = 8;  tl = t - 512; }
    const int bx = tl % nx, by = tl / nx;
    const int n0 = bx << 6, k0 = by << 6;
    const int xl = tid & 15, yl = tid >> 4;
#pragma unroll
    for (int r = 0; r < 4; ++r) {
      const int row = yl + r * 16;
      const f32x4 vv = *(const f32x4*)&W[(size_t)(k0 + row) * N + n0 + xl * 4];
#pragma unroll
      for (int e = 0; e < 4; ++e)
        tile[row * 65 + xl * 4 + e] = vv[e];
    }
    __syncthreads();
    const int xk = tid & 7, nl = tid >> 3;
#pragma unroll
    for (int r2 = 0; r2 < 2; ++r2) {
      const int n = nl + r2 * 32;
      bf16x8 o;
#pragma unroll
      for (int e = 0; e < 8; ++e)
        o[e] = (bf16)tile[(xk * 8 + e) * 65 + n];
      *(bf16x8*)&Wt[(size_t)(n0 + n) * K + k0 + xk * 8] = o;
    }
    return;
  }
  // ---- gather [v,b,c,h,w] -> [b,t,c] + LN1  (xcd == b)
  const int u = t - 768;
  const int sel = u >> 8, bid = u & 255;
  const int b = bid & 7, hp = (bid >> 3) & 7, v = bid >> 6;
  const float* src = (sel == 0) ? xi : ((sel == 1) ? xj : xc);
  const size_t base = ((size_t)(v * 8 + b) * 512) * 256 + hp * 32;
  const int q8 = tid & 7, chb = tid >> 3;
  const int wid = tid >> 6, lc = (tid >> 3) & 7;
  const int cb = chb << 4;

  float gr[16], br[16];
#pragma unroll
  for (int p = 0; p < 4; ++p) {
    *(f32x4*)&gr[p * 4] = *(const f32x4*)&g[cb + p * 4];
    *(f32x4*)&br[p * 4] = *(const f32x4*)&bb[cb + p * 4];
  }
  f32x4 x[16];
#pragma unroll
  for (int k = 0; k < 16; ++k)
    x[k] = *(const f32x4*)&src[base + (size_t)(cb + k) * 256 + q8 * 4];

  float s[4] = {0.f, 0.f, 0.f, 0.f}, ss[4] = {0.f, 0.f, 0.f, 0.f};
#pragma unroll
  for (int k = 0; k < 16; ++k)
#pragma unroll
    for (int i = 0; i < 4; ++i) {
      s[i] += x[k][i];
      ss[i] += x[k][i] * x[k][i];
    }
#pragma unroll
  for (int off = 8; off < 64; off <<= 1)
#pragma unroll
    for (int i = 0; i < 4; ++i) {
      s[i] += __shfl_xor(s[i], off);
      ss[i] += __shfl_xor(ss[i], off);
    }
  if (lc < 4)      red[wid][q8 * 4 + lc]            = s[lc];
  else             red[wid][32 + q8 * 4 + (lc - 4)] = ss[lc - 4];
  __syncthreads();
  f32x4 st = {0.f, 0.f, 0.f, 0.f}, sst = {0.f, 0.f, 0.f, 0.f};
#pragma unroll
  for (int w = 0; w < 4; ++w) {
    st  += *(const f32x4*)&red[w][q8 * 4];
    sst += *(const f32x4*)&red[w][32 + q8 * 4];
  }
  float mu[4], rs[4];
#pragma unroll
  for (int i = 0; i < 4; ++i) {
    mu[i] = st[i] * (1.f / 512.f);
    rs[i] = rsqrtf(sst[i] * (1.f / 512.f) - mu[i] * mu[i] + 1e-5f);
  }
  bf16* dstb = (sel == 0) ? qs : ((sel == 1) ? kvs : csb);
  const int tkb = v * 256 + hp * 32 + q8 * 4;
#pragma unroll
  for (int i = 0; i < 4; ++i) {
    const size_t orow = ((size_t)b * 1024 + tkb + i) * 512 + cb;
    bf16x8 o0, o1;
#pragma unroll
    for (int k = 0; k < 8; ++k) {
      o0[k] = (bf16)((x[k][i] - mu[i]) * rs[i] * gr[k] + br[k]);
      o1[k] = (bf16)((x[k + 8][i] - mu[i]) * rs[i] * gr[k + 8] + br[k + 8]);
    }
    *(bf16x8*)&dstb[orow]     = o0;
    *(bf16x8*)&dstb[orow + 8] = o1;
  }
}

// ---------------------------------------------------------------------------
// Kernel 3: row LayerNorm(ln2), xcd == b.
// ---------------------------------------------------------------------------
__global__ __launch_bounds__(256)
void ln2_k(const bf16* __restrict__ cs, const float* __restrict__ g,
           const float* __restrict__ bb, bf16* __restrict__ hcs)
{
  const int tid = threadIdx.x, wid = tid >> 6, lane = tid & 63;
  const int bid = blockIdx.x;
  const int xcd = bid & 7, c2 = bid >> 3;
  const int row = xcd * 1024 + c2 * 4 + wid;
  const bf16x8 v8 = *(const bf16x8*)&cs[(size_t)row * 512 + lane * 8];
  float v[8];
#pragma unroll
  for (int k = 0; k < 8; ++k) v[k] = (float)v8[k];
  float s = 0.f, ss = 0.f;
#pragma unroll
  for (int k = 0; k < 8; ++k) { s += v[k]; ss += v[k] * v[k]; }
#pragma unroll
  for (int off = 1; off < 64; off <<= 1) {
    s += __shfl_xor(s, off);
    ss += __shfl_xor(ss, off);
  }
  const float mu = s * (1.f / 512.f);
  const float rstd = rsqrtf(ss * (1.f / 512.f) - mu * mu + 1e-5f);
  bf16x8 o;
#pragma unroll
  for (int k = 0; k < 8; ++k) {
    int ch = lane * 8 + k;
    o[k] = (bf16)((v[k] - mu) * rstd * g[ch] + bb[ch]);
  }
  *(bf16x8*)&hcs[(size_t)row * 512 + lane * 8] = o;
}

// ---------------------------------------------------------------------------
// Kernel 4: FC GEMM (M=8192, N=2048, K=512). 128x256 tile, 8 waves, 3-deep
// counted-vmcnt pipeline (L=3). GELU epilogue via padded LDS overlay.
// ---------------------------------------------------------------------------
__global__ __launch_bounds__(512)
void gemm_fc_k(const bf16* __restrict__ A, const bf16* __restrict__ Bt,
               const float* __restrict__ bias, bf16* __restrict__ fo)
{
  const int K = 512;
  __shared__ __align__(16) char smem[73728]; // 72 KB
  bf16* As = (bf16*)smem;            // [3][4096] = 24 KB
  bf16* Bs = (bf16*)(smem + 24576);  // [3][8192] = 48 KB
  bf16* OT = (bf16*)smem;            // [128][264] overlay (post-loop)
  const int tid = threadIdx.x;
  const int wid = tid >> 6, lane = tid & 63;
  const int wr = wid >> 2, wcc = wid & 3;
  const int ml = lane & 15, kg = (lane >> 4) << 3;
  const int bid = blockIdx.x;
  const int xcd = bid & 7, chunk = bid >> 3;
  const int m0 = (xcd * 8 + (chunk & 7)) * 128;
  const int n0 = (chunk >> 3) * 256;

  const int rA = (wid << 4) + (lane >> 2), cA = (lane & 3) << 3;
  const bf16* Ag = A + (size_t)m0 * K;
  const bf16* Bg = Bt + (size_t)n0 * K;

  f32x4 acc[4][4] = {};

#define FC_STAGE(kk, bu)                                                      \
  do {                                                                        \
    gload_lds16(Ag + (size_t)rA * K + (kk) + cA,         As + (bu) * 4096 + wid * 512); \
    gload_lds16(Bg + (size_t)rA * K + (kk) + cA,         Bs + (bu) * 8192 + wid * 512); \
    gload_lds16(Bg + (size_t)(rA + 128) * K + (kk) + cA, Bs + (bu) * 8192 + 4096 + wid * 512); \
  } while (0)

  FC_STAGE(0, 0);
  FC_STAGE(32, 1);

  for (int kt = 0; kt < 16; ++kt) {
    if (kt == 15) VM_FENCE(0); else VM_FENCE(3);
    if (kt + 2 < 16) FC_STAGE((kt + 2) * 32, (kt + 2) % 3);
    const int cur = kt % 3;
    bf16x8 af[4], bfr[4];
#pragma unroll
    for (int mf = 0; mf < 4; ++mf)
      af[mf] = *(const bf16x8*)&As[cur * 4096 + (wr * 64 + mf * 16 + ml) * 32 + kg];
#pragma unroll
    for (int nf = 0; nf < 4; ++nf)
      bfr[nf] = *(const bf16x8*)&Bs[cur * 8192 + (wcc * 64 + nf * 16 + ml) * 32 + kg];
#pragma unroll
    for (int mf = 0; mf < 4; ++mf)
#pragma unroll
      for (int nf = 0; nf < 4; ++nf)
        acc[mf][nf] = __builtin_amdgcn_mfma_f32_16x16x32_bf16(
            af[mf], bfr[nf], acc[mf][nf], 0, 0, 0);
  }
#undef FC_STAGE

  __syncthreads();
  const int jrow0 = (lane >> 4) << 2;
#pragma unroll
  for (int nf = 0; nf < 4; ++nf) {
    const float bv = bias[n0 + wcc * 64 + nf * 16 + ml];
#pragma unroll
    for (int mf = 0; mf < 4; ++mf)
#pragma unroll
      for (int j = 0; j < 4; ++j) {
        float x = acc[mf][nf][j] + bv;
        float u = 0.7978845608f * (x + 0.044715f * x * x * x);
        float e = __expf(2.f * u);
        float th = 1.f - 2.f / (e + 1.f);
        OT[(wr * 64 + mf * 16 + jrow0 + j) * 264 + wcc * 64 + nf * 16 + ml] =
            (bf16)(0.5f * x * (1.f + th));
      }
  }
  __syncthreads();
#pragma unroll
  for (int it = 0; it < 8; ++it) {
    const int idx = it * 512 + tid;
    const int cg = idx & 31, r = idx >> 5;
    *(bf16x8*)&fo[(size_t)(m0 + r) * 2048 + n0 + cg * 8] =
        *(const bf16x8*)&OT[r * 264 + cg * 8];
  }
}

// ---------------------------------------------------------------------------
// Kernel 4b: split-K GEMM for N=512 stages (O, PR). BM=64, BN=128, grid 512,
// 3-deep counted-vmcnt pipeline (L=3) per K-half group.
// ---------------------------------------------------------------------------
enum { EPI_O = 2, EPI_PR = 4 };

template <int EPI>
__global__ __launch_bounds__(512)
void gemmsk_k(const bf16* __restrict__ A, const bf16* __restrict__ Bt,
              const float* __restrict__ bias, const bf16* res,
              void* out0, int K)
{
  __shared__ __align__(16) char smem[73728]; // 72 KB
  bf16*  AS = (bf16*)smem;            // [3][2 half][2048] = 24 KB
  bf16*  BS = (bf16*)(smem + 24576);  // [3][2 half][4096] = 48 KB
  float* CF = (float*)smem;           // f32[64][128] overlay (post-loop)

  const int tid = threadIdx.x;
  const int wid = tid >> 6, lane = tid & 63;
  const int half = wid >> 2, w2 = wid & 3;
  const int wr = w2 >> 1, wc = w2 & 1;
  const int ml = lane & 15, kg = (lane >> 4) << 3;
  const int bid = blockIdx.x;
  const int xcd = bid & 7, chunk = bid >> 3;
  const int m0 = (xcd * 16 + (chunk & 15)) * 64;
  const int n0 = (chunk >> 4) * 128;
  const int Kh = K >> 1;
  const int NK = Kh >> 5;

  const int eA = w2 * 512 + lane * 8;
  const int rA = eA >> 5, cA = eA & 31;
  const int eB0 = (w2 * 2) * 512 + lane * 8;
  const int rB0 = eB0 >> 5, cB0 = eB0 & 31;
  const int eB1 = eB0 + 512;
  const int rB1 = eB1 >> 5, cB1 = eB1 & 31;

  const bf16* Ag = A + (size_t)m0 * K + half * Kh;
  const bf16* Bg = Bt + (size_t)n0 * K + half * Kh;

  f32x4 acc[2][4] = {};

#define SK_STAGE(kk, bu)                                                      \
  do {                                                                        \
    gload_lds16(Ag + (size_t)rA * K + (kk) + cA,   AS + (bu) * 4096 + half * 2048 + w2 * 512); \
    gload_lds16(Bg + (size_t)rB0 * K + (kk) + cB0, BS + (bu) * 8192 + half * 4096 + (w2 * 2) * 512); \
    gload_lds16(Bg + (size_t)rB1 * K + (kk) + cB1, BS + (bu) * 8192 + half * 4096 + (w2 * 2 + 1) * 512); \
  } while (0)

  SK_STAGE(0, 0);
  SK_STAGE(32, 1);

  for (int kt = 0; kt < NK; ++kt) {
    if (kt == NK - 1) VM_FENCE(0); else VM_FENCE(3);
    if (kt + 2 < NK) SK_STAGE((kt + 2) * 32, (kt + 2) % 3);
    const int cur = kt % 3;
    const bf16* Ac = AS + cur * 4096 + half * 2048;
    const bf16* Bc = BS + cur * 8192 + half * 4096;
    bf16x8 af[2], bfr[4];
#pragma unroll
    for (int mf = 0; mf < 2; ++mf)
      af[mf] = *(const bf16x8*)&Ac[(wr * 32 + mf * 16 + ml) * 32 + kg];
#pragma unroll
    for (int nf = 0; nf < 4; ++nf)
      bfr[nf] = *(const bf16x8*)&Bc[(wc * 64 + nf * 16 + ml) * 32 + kg];
#pragma unroll
    for (int mf = 0; mf < 2; ++mf)
#pragma unroll
      for (int nf = 0; nf < 4; ++nf)
        acc[mf][nf] = __builtin_amdgcn_mfma_f32_16x16x32_bf16(
            af[mf], bfr[nf], acc[mf][nf], 0, 0, 0);
  }
#undef SK_STAGE

  const int jrow0 = (lane >> 4) << 2;
  __syncthreads(); // staging dead; CF may overlay AS/BS
  if (half == 0) {
#pragma unroll
    for (int mf = 0; mf < 2; ++mf)
#pragma unroll
      for (int nf = 0; nf < 4; ++nf)
#pragma unroll
        for (int j = 0; j < 4; ++j)
          CF[(wr * 32 + mf * 16 + jrow0 + j) * 128 + wc * 64 + nf * 16 + ml] =
              acc[mf][nf][j];
  }
  __syncthreads();
  if (half == 1) {
#pragma unroll
    for (int nf = 0; nf < 4; ++nf) {
      const int n = n0 + wc * 64 + nf * 16 + ml;
      const float bv = bias[n];
#pragma unroll
      for (int mf = 0; mf < 2; ++mf) {
        const int mbase = m0 + wr * 32 + mf * 16 + jrow0;
        float v4[4];
#pragma unroll
        for (int j = 0; j < 4; ++j)
          v4[j] = acc[mf][nf][j] +
                  CF[(wr * 32 + mf * 16 + jrow0 + j) * 128 + wc * 64 + nf * 16 + ml];
        if constexpr (EPI == EPI_O) {
          bf16* cs = (bf16*)out0; // in-place with res
#pragma unroll
          for (int j = 0; j < 4; ++j) {
            const size_t idx = (size_t)(mbase + j) * 512 + n;
            cs[idx] = (bf16)(v4[j] + bv + (float)res[idx]);
          }
        } else {
          float* out = (float*)out0;
          const int b = mbase >> 10, t = mbase & 1023;
          const int v = t >> 8, hhh = (t >> 4) & 15, w0 = t & 15;
          f32x4 o;
#pragma unroll
          for (int j = 0; j < 4; ++j)
            o[j] = v4[j] + bv + (float)res[(size_t)(mbase + j) * 512 + n];
          *(f32x4*)&out[(((size_t)v * 8 + b) * 512 + n) * 256 + hhh * 16 + w0] = o;
        }
      }
    }
  }
}

// ---------------------------------------------------------------------------
// Kernel 4c: merged Q + KV projection GEMM, 3-deep counted-vmcnt (L=4),
// LDS-staged stores. Grid 768, xcd == b.
// ---------------------------------------------------------------------------
__global__ __launch_bounds__(256)
void gemm_qkv_k(const bf16* __restrict__ Aq, const bf16* __restrict__ Akv,
                const bf16* __restrict__ WqT, const bf16* __restrict__ WkvT,
                const float* __restrict__ bq, const float* __restrict__ bkv,
                bf16* __restrict__ q_buf, bf16* __restrict__ k_buf,
                bf16* __restrict__ v_t)
{
  const int K = 512;
  __shared__ __align__(16) char smem[49152]; // 48 KB
  bf16* As = (bf16*)smem;            // [3][4096] = 24 KB
  bf16* Bs = (bf16*)(smem + 24576);  // [3][4096] = 24 KB
  const int tid = threadIdx.x;
  const int wid = tid >> 6, lane = tid & 63;
  const int wr = wid >> 1, wc = wid & 1;
  const int ml = lane & 15, kg = (lane >> 4) << 3;
  const int bid = blockIdx.x;
  const int xcd = bid & 7, chunk = bid >> 3;
  const int m0 = (xcd * 8 + (chunk & 7)) * 128;
  const int ybl = chunk >> 3;
  const bool isq = ybl < 4;
  const bf16* A     = isq ? Aq  : Akv;
  const bf16* Bt    = isq ? WqT : WkvT;
  const float* bias = isq ? bq : bkv;
  const int n0 = isq ? (ybl << 7) : ((ybl - 4) << 7);

  const int e0 = wid * 512 + lane * 8;
  const int r0 = e0 >> 5, c0 = e0 & 31;
  const int e1 = e0 + 2048;
  const int r1 = e1 >> 5, c1 = e1 & 31;

  const bf16* Ag = A + (size_t)m0 * K;
  const bf16* Bg = Bt + (size_t)n0 * K;

  f32x4 acc[4][4] = {};

#define QKV_STAGE(kk, bu)                                                     \
  do {                                                                        \
    gload_lds16(Ag + (size_t)r0 * K + (kk) + c0, As + (bu) * 4096 + wid * 512); \
    gload_lds16(Ag + (size_t)r1 * K + (kk) + c1, As + (bu) * 4096 + 2048 + wid * 512); \
    gload_lds16(Bg + (size_t)r0 * K + (kk) + c0, Bs + (bu) * 4096 + wid * 512); \
    gload_lds16(Bg + (size_t)r1 * K + (kk) + c1, Bs + (bu) * 4096 + 2048 + wid * 512); \
  } while (0)

  QKV_STAGE(0, 0);
  QKV_STAGE(32, 1);

  for (int kt = 0; kt < 16; ++kt) {
    if (kt == 15) VM_FENCE(0); else VM_FENCE(4);
    if (kt + 2 < 16) QKV_STAGE((kt + 2) * 32, (kt + 2) % 3);
    const int cur = kt % 3;
    bf16x8 af[4], bfr[4];
#pragma unroll
    for (int mf = 0; mf < 4; ++mf)
      af[mf] = *(const bf16x8*)&As[cur * 4096 + (wr * 64 + mf * 16 + ml) * 32 + kg];
#pragma unroll
    for (int nf = 0; nf < 4; ++nf)
      bfr[nf] = *(const bf16x8*)&Bs[cur * 4096 + (wc * 64 + nf * 16 + ml) * 32 + kg];
#pragma unroll
    for (int mf = 0; mf < 4; ++mf)
#pragma unroll
      for (int nf = 0; nf < 4; ++nf)
        acc[mf][nf] = __builtin_amdgcn_mfma_f32_16x16x32_bf16(
            af[mf], bfr[nf], acc[mf][nf], 0, 0, 0);
  }
#undef QKV_STAGE

  __syncthreads();
  bf16* OT = (bf16*)smem; // [128][132] padded overlay
  const int jrow0 = (lane >> 4) << 2;
  const int b = m0 >> 10, t0 = m0 & 1023;
  if (ybl < 8) { // Q or K: stage row-major (row=m, col=n)
#pragma unroll
    for (int nf = 0; nf < 4; ++nf) {
      const float bv = bias[n0 + wc * 64 + nf * 16 + ml];
#pragma unroll
      for (int mf = 0; mf < 4; ++mf)
#pragma unroll
        for (int j = 0; j < 4; ++j)
          OT[(wr * 64 + mf * 16 + jrow0 + j) * 132 + wc * 64 + nf * 16 + ml] =
              (bf16)(acc[mf][nf][j] + bv);
    }
    __syncthreads();
    bf16* dst = isq ? q_buf : k_buf;
    const int h0 = n0 >> 6;
#pragma unroll
    for (int it = 0; it < 8; ++it) {
      const int idx = it * 256 + tid;
      const int dg = idx & 7, r = (idx >> 3) & 127, hl = idx >> 10;
      *(bf16x8*)&dst[(((size_t)b * 8 + h0 + hl) * 1024 + t0 + r) * 64 + dg * 8] =
          *(const bf16x8*)&OT[r * 132 + hl * 64 + dg * 8];
    }
  } else { // V: stage col-major for t-contiguous stores
#pragma unroll
    for (int nf = 0; nf < 4; ++nf) {
      const float bv = bias[n0 + wc * 64 + nf * 16 + ml];
#pragma unroll
      for (int mf = 0; mf < 4; ++mf) {
        bf16x4 o;
#pragma unroll
        for (int j = 0; j < 4; ++j) o[j] = (bf16)(acc[mf][nf][j] + bv);
        *(bf16x4*)&OT[(wc * 64 + nf * 16 + ml) * 132 + wr * 64 + mf * 16 + jrow0] = o;
      }
    }
    __syncthreads();
    const int h0 = (n0 - 512) >> 6;
#pragma unroll
    for (int it = 0; it < 8; ++it) {
      const int idx = it * 256 + tid;
      const int og = idx & 15, c = idx >> 4;
      const int hl = c >> 6, d = c & 63;
      *(bf16x8*)&v_t[(((size_t)b * 8 + h0 + hl) * 64 + d) * 1024 + t0 + og * 8] =
          *(const bf16x8*)&OT[c * 132 + og * 8];
    }
  }
}

// ---------------------------------------------------------------------------
// Kernel 5: block-causal flash attention, QBLK=128 (8 waves, 512 threads),
// 3-deep counted-vmcnt K/V pipeline (VM_FENCE(2) per tile).
// ---------------------------------------------------------------------------
__global__ __launch_bounds__(512)
void attn_k(const bf16* __restrict__ qb, const bf16* __restrict__ kb,
            const bf16* __restrict__ vt, bf16* __restrict__ y)
{
  __shared__ bf16 Ks[3][4096];
  __shared__ bf16 Vs[3][4096];
  __shared__ bf16 Ps[8][1024];
  const int tid = threadIdx.x, wid = tid >> 6, lane = tid & 63;
  const int L = blockIdx.x;                  // 0..511
  const int xcd = L & 7, chunk = L >> 3;     // chunk 0..63
  const int bh = (xcd << 3) + (chunk >> 3);  // b == xcd
  const int qt = 7 - (chunk & 7);            // long blocks first
  const int b = bh >> 3, h = bh & 7;
  const int t0 = qt << 7;
  const int ml = lane & 15, hi = lane >> 4, kg = hi << 3;

  const bf16* qrow = qb + ((size_t)bh * 1024 + t0 + wid * 16) * 64;
  bf16x8 aq[2];
  aq[0] = *(const bf16x8*)&qrow[ml * 64 + kg];
  aq[1] = *(const bf16x8*)&qrow[ml * 64 + 32 + kg];

  f32x4 accO[4] = {};
  float lsum[4] = {0.f, 0.f, 0.f, 0.f};

  const int nkt = ((qt >> 1) + 1) << 2;      // 4..16 tiles of 64 tokens
  const bf16* kbase = kb + (size_t)bh * 1024 * 64;
  const bf16* vbase = vt + (size_t)bh * 64 * 1024;

  const int sr = tid >> 3;                       // 0..63
  const int sg = ((tid & 7) ^ (sr & 7)) << 3;    // swizzled granule (elems)
  bf16* pw = &Ps[wid][0];

#define AT_STAGE(tk0, bu)                                                     \
  do {                                                                        \
    gload_lds16(kbase + (size_t)((tk0) + sr) * 64 + sg,  &Ks[bu][wid * 512]); \
    gload_lds16(vbase + (size_t)sr * 1024 + (tk0) + sg,  &Vs[bu][wid * 512]); \
  } while (0)

  AT_STAGE(0, 0);
  AT_STAGE(64, 1);   // nkt >= 4 always

  for (int kt = 0; kt < nkt; ++kt) {
    if (kt == nkt - 1) VM_FENCE(0); else VM_FENCE(2);
    if (kt + 2 < nkt) AT_STAGE((kt + 2) << 6, (kt + 2) % 3);
    const int cur = kt % 3;

    f32x4 sa[4] = {};
    __builtin_amdgcn_s_setprio(1);
#pragma unroll
    for (int nf = 0; nf < 4; ++nf) {
      const int row = nf * 16 + ml;
#pragma unroll
      for (int ks = 0; ks < 2; ++ks) {
        const int g = ((ks * 4 + hi) ^ (ml & 7)) << 3;
        bf16x8 bk = *(const bf16x8*)&Ks[cur][row * 64 + g];
        sa[nf] = __builtin_amdgcn_mfma_f32_16x16x32_bf16(aq[ks], bk, sa[nf], 0, 0, 0);
      }
    }
    __builtin_amdgcn_s_setprio(0);

#pragma unroll
    for (int nf = 0; nf < 4; ++nf) {
      const int gp0 = nf * 2 + (ml >> 3);
#pragma unroll
      for (int j = 0; j < 4; ++j) {
        const float p = __expf(sa[nf][j] * 0.125f);
        lsum[j] += p;
        const int prow = (hi << 2) + j;
        pw[prow * 64 + ((gp0 ^ (prow & 7)) << 3) + (ml & 7)] = (bf16)p;
      }
    }

    __builtin_amdgcn_s_setprio(1);
#pragma unroll
    for (int ks = 0; ks < 2; ++ks) {
      const int g = ((ks * 4 + hi) ^ (ml & 7)) << 3;
      bf16x8 pa = *(const bf16x8*)&pw[ml * 64 + g];
#pragma unroll
      for (int df = 0; df < 4; ++df) {
        bf16x8 bv = *(const bf16x8*)&Vs[cur][(df * 16 + ml) * 64 + g];
        accO[df] = __builtin_amdgcn_mfma_f32_16x16x32_bf16(pa, bv, accO[df], 0, 0, 0);
      }
    }
    __builtin_amdgcn_s_setprio(0);
  }
#undef AT_STAGE

  float inv[4];
#pragma unroll
  for (int j = 0; j < 4; ++j) {
    float s = lsum[j];
#pragma unroll
    for (int off = 1; off < 16; off <<= 1) s += __shfl_xor(s, off);
    inv[j] = 1.f / s;
  }
#pragma unroll
  for (int df = 0; df < 4; ++df)
#pragma unroll
    for (int j = 0; j < 4; ++j) {
      const int t = t0 + wid * 16 + (hi << 2) + j;
      const int c = h * 64 + df * 16 + ml;
      y[((size_t)b * 1024 + t) * 512 + c] = (bf16)(accO[df][j] * inv[j]);
    }
}

// ---------------------------------------------------------------------------
extern "C" void kernel_launch(void* const* d_in, const int* in_sizes, int n_in,
                              void* d_out, int out_size, void* d_ws, size_t ws_size,
                              hipStream_t stream)
{
  const float* xi    = (const float*)d_in[0];
  const float* xc    = (const float*)d_in[1];
  const float* xj    = (const float*)d_in[2];
  const float* ln1_g = (const float*)d_in[3];
  const float* ln1_b = (const float*)d_in[4];
  const float* ln2_g = (const float*)d_in[5];
  const float* ln2_b = (const float*)d_in[6];
  const float* Wq    = (const float*)d_in[7];
  const float* bq    = (const float*)d_in[8];
  const float* Wkv   = (const float*)d_in[9];
  const float* bkv   = (const float*)d_in[10];
  const float* Wo    = (const float*)d_in[11];
  const float* bo    = (const float*)d_in[12];
  const float* Wfc   = (const float*)d_in[13];
  const float* bfc   = (const float*)d_in[14];
  const float* Wpr   = (const float*)d_in[15];
  const float* bpr   = (const float*)d_in[16];

  char* ws = (char*)d_ws;
  const size_t MB = 1ull << 20;
  bf16*  qs    = (bf16*)(ws + 0);                  // 8 MB
  bf16*  kvs   = (bf16*)(ws + 8 * MB);             // 8 MB
  bf16*  csb   = (bf16*)(ws + 16 * MB);            // 8 MB (bf16 residual)
  bf16*  WqT   = (bf16*)(ws + 32 * MB);
  bf16*  WkvT  = (bf16*)(ws + 32 * MB + 512 * 1024);
  bf16*  WoT   = (bf16*)(ws + 33 * MB + 512 * 1024);
  bf16*  WfcT  = (bf16*)(ws + 34 * MB);
  bf16*  WprT  = (bf16*)(ws + 36 * MB);
  bf16*  q_buf = (bf16*)(ws + 38 * MB);
  bf16*  k_buf = (bf16*)(ws + 46 * MB);
  bf16*  v_t   = (bf16*)(ws + 54 * MB);
  bf16*  yb    = (bf16*)(ws + 0);                  // reuse qs
  bf16*  hcs   = (bf16*)(ws + 8 * MB);             // reuse kvs
  bf16*  fcact = (bf16*)(ws + 38 * MB);            // reuse q/k/v

  prep_k<<<dim3(1536), 256, 0, stream>>>(Wq, Wkv, Wo, Wfc, Wpr,
                                         WqT, WkvT, WoT, WfcT, WprT,
                                         xi, xj, xc, ln1_g, ln1_b, qs, kvs, csb);

  gemm_qkv_k<<<dim3(768), 256, 0, stream>>>(qs, kvs, WqT, WkvT, bq, bkv,
                                            q_buf, k_buf, v_t);

  attn_k<<<dim3(512), 512, 0, stream>>>(q_buf, k_buf, v_t, yb);

  gemmsk_k<EPI_O><<<dim3(512), 512, 0, stream>>>(yb, WoT, bo, csb,
                                                 (void*)csb, 512);

  ln2_k<<<dim3(2048), 256, 0, stream>>>(csb, ln2_g, ln2_b, hcs);

  gemm_fc_k<<<dim3(512), 512, 0, stream>>>(hcs, WfcT, bfc, fcact);

  gemmsk_k<EPI_PR><<<dim3(512), 512, 0, stream>>>(fcact, WprT, bpr, csb,
                                                  d_out, 2048);

  (void)in_sizes; (void)n_in; (void)out_size; (void)ws_size;
}

// Round 17
// 148.608 us; speedup vs baseline: 1.0185x; 1.0185x over previous
//
#include <hip/hip_runtime.h>
#include <hip/hip_bf16.h>
#include <math.h>

// ---------------------------------------------------------------------------
// CrossCausalAttentionBlock on MI355X (gfx950)
// B=8, T=1024 (V=4 blocks of 256), C=512, NH=8, hd=64
// R17: attn reverted to R15 2-buffer form (R16 counted-vmcnt was neutral);
//      LDS-restaged epilogue stores for PR (f32 256B runs), O (bf16 256B
//      rows), attn y (128B rows via P buffer). Bit-identical math.
// ---------------------------------------------------------------------------

typedef __bf16 bf16;
typedef __bf16 bf16x8 __attribute__((ext_vector_type(8)));
typedef __bf16 bf16x4 __attribute__((ext_vector_type(4)));
typedef float  f32x4  __attribute__((ext_vector_type(4)));

__device__ __forceinline__ void gload_lds16(const void* g, void* l) {
  __builtin_amdgcn_global_load_lds(
      (__attribute__((address_space(1))) void*)(g),
      (__attribute__((address_space(3))) void*)(l), 16, 0, 0);
}

#define VM_FENCE(N)                                              \
  do {                                                           \
    asm volatile("s_waitcnt vmcnt(" #N ")" ::: "memory");        \
    __builtin_amdgcn_sched_barrier(0);                           \
    __builtin_amdgcn_s_barrier();                                \
    __builtin_amdgcn_sched_barrier(0);                           \
  } while (0)

// ---------------------------------------------------------------------------
// Kernel 1: prep. Blocks 0..767: weight convert 64x64 tiles. 768..1535:
// gather+LN1 h-pair blocks (register-resident, vector loads/stores).
// ---------------------------------------------------------------------------
__global__ __launch_bounds__(256)
void prep_k(const float* __restrict__ Wq, const float* __restrict__ Wkv,
            const float* __restrict__ Wo, const float* __restrict__ Wfc,
            const float* __restrict__ Wpr,
            bf16* __restrict__ WqT, bf16* __restrict__ WkvT,
            bf16* __restrict__ WoT, bf16* __restrict__ WfcT,
            bf16* __restrict__ WprT,
            const float* __restrict__ xi, const float* __restrict__ xj,
            const float* __restrict__ xc,
            const float* __restrict__ g, const float* __restrict__ bb,
            bf16* __restrict__ qs, bf16* __restrict__ kvs,
            bf16* __restrict__ csb)
{
  __shared__ float tile[64 * 65];
  __shared__ float red[4][64];
  const int t = blockIdx.x;
  const int tid = threadIdx.x;
  if (t < 768) { // ---- weight transpose-convert, 64x64 tiles
    const float* W; bf16* Wt; int K, N, nx, tl;
    if (t < 64)        { W = Wq;  Wt = WqT;  K = 512;  N = 512;  nx = 8;  tl = t; }
    else if (t < 192)  { W = Wkv; Wt = WkvT; K = 512;  N = 1024; nx = 16; tl = t - 64; }
    else if (t < 256)  { W = Wo;  Wt = WoT;  K = 512;  N = 512;  nx = 8;  tl = t - 192; }
    else if (t < 512)  { W = Wfc; Wt = WfcT; K = 512;  N = 2048; nx = 32; tl = t - 256; }
    else               { W = Wpr; Wt = WprT; K = 2048; N = 512;  nx = 8;  tl = t - 512; }
    const int bx = tl % nx, by = tl / nx;
    const int n0 = bx << 6, k0 = by << 6;
    const int xl = tid & 15, yl = tid >> 4;
#pragma unroll
    for (int r = 0; r < 4; ++r) {
      const int row = yl + r * 16;
      const f32x4 vv = *(const f32x4*)&W[(size_t)(k0 + row) * N + n0 + xl * 4];
#pragma unroll
      for (int e = 0; e < 4; ++e)
        tile[row * 65 + xl * 4 + e] = vv[e];
    }
    __syncthreads();
    const int xk = tid & 7, nl = tid >> 3;
#pragma unroll
    for (int r2 = 0; r2 < 2; ++r2) {
      const int n = nl + r2 * 32;
      bf16x8 o;
#pragma unroll
      for (int e = 0; e < 8; ++e)
        o[e] = (bf16)tile[(xk * 8 + e) * 65 + n];
      *(bf16x8*)&Wt[(size_t)(n0 + n) * K + k0 + xk * 8] = o;
    }
    return;
  }
  // ---- gather [v,b,c,h,w] -> [b,t,c] + LN1  (xcd == b)
  const int u = t - 768;
  const int sel = u >> 8, bid = u & 255;
  const int b = bid & 7, hp = (bid >> 3) & 7, v = bid >> 6;
  const float* src = (sel == 0) ? xi : ((sel == 1) ? xj : xc);
  const size_t base = ((size_t)(v * 8 + b) * 512) * 256 + hp * 32;
  const int q8 = tid & 7, chb = tid >> 3;
  const int wid = tid >> 6, lc = (tid >> 3) & 7;
  const int cb = chb << 4;

  float gr[16], br[16];
#pragma unroll
  for (int p = 0; p < 4; ++p) {
    *(f32x4*)&gr[p * 4] = *(const f32x4*)&g[cb + p * 4];
    *(f32x4*)&br[p * 4] = *(const f32x4*)&bb[cb + p * 4];
  }
  f32x4 x[16];
#pragma unroll
  for (int k = 0; k < 16; ++k)
    x[k] = *(const f32x4*)&src[base + (size_t)(cb + k) * 256 + q8 * 4];

  float s[4] = {0.f, 0.f, 0.f, 0.f}, ss[4] = {0.f, 0.f, 0.f, 0.f};
#pragma unroll
  for (int k = 0; k < 16; ++k)
#pragma unroll
    for (int i = 0; i < 4; ++i) {
      s[i] += x[k][i];
      ss[i] += x[k][i] * x[k][i];
    }
#pragma unroll
  for (int off = 8; off < 64; off <<= 1)
#pragma unroll
    for (int i = 0; i < 4; ++i) {
      s[i] += __shfl_xor(s[i], off);
      ss[i] += __shfl_xor(ss[i], off);
    }
  if (lc < 4)      red[wid][q8 * 4 + lc]            = s[lc];
  else             red[wid][32 + q8 * 4 + (lc - 4)] = ss[lc - 4];
  __syncthreads();
  f32x4 st = {0.f, 0.f, 0.f, 0.f}, sst = {0.f, 0.f, 0.f, 0.f};
#pragma unroll
  for (int w = 0; w < 4; ++w) {
    st  += *(const f32x4*)&red[w][q8 * 4];
    sst += *(const f32x4*)&red[w][32 + q8 * 4];
  }
  float mu[4], rs[4];
#pragma unroll
  for (int i = 0; i < 4; ++i) {
    mu[i] = st[i] * (1.f / 512.f);
    rs[i] = rsqrtf(sst[i] * (1.f / 512.f) - mu[i] * mu[i] + 1e-5f);
  }
  bf16* dstb = (sel == 0) ? qs : ((sel == 1) ? kvs : csb);
  const int tkb = v * 256 + hp * 32 + q8 * 4;
#pragma unroll
  for (int i = 0; i < 4; ++i) {
    const size_t orow = ((size_t)b * 1024 + tkb + i) * 512 + cb;
    bf16x8 o0, o1;
#pragma unroll
    for (int k = 0; k < 8; ++k) {
      o0[k] = (bf16)((x[k][i] - mu[i]) * rs[i] * gr[k] + br[k]);
      o1[k] = (bf16)((x[k + 8][i] - mu[i]) * rs[i] * gr[k + 8] + br[k + 8]);
    }
    *(bf16x8*)&dstb[orow]     = o0;
    *(bf16x8*)&dstb[orow + 8] = o1;
  }
}

// ---------------------------------------------------------------------------
// Kernel 3: row LayerNorm(ln2), xcd == b.
// ---------------------------------------------------------------------------
__global__ __launch_bounds__(256)
void ln2_k(const bf16* __restrict__ cs, const float* __restrict__ g,
           const float* __restrict__ bb, bf16* __restrict__ hcs)
{
  const int tid = threadIdx.x, wid = tid >> 6, lane = tid & 63;
  const int bid = blockIdx.x;
  const int xcd = bid & 7, c2 = bid >> 3;
  const int row = xcd * 1024 + c2 * 4 + wid;
  const bf16x8 v8 = *(const bf16x8*)&cs[(size_t)row * 512 + lane * 8];
  float v[8];
#pragma unroll
  for (int k = 0; k < 8; ++k) v[k] = (float)v8[k];
  float s = 0.f, ss = 0.f;
#pragma unroll
  for (int k = 0; k < 8; ++k) { s += v[k]; ss += v[k] * v[k]; }
#pragma unroll
  for (int off = 1; off < 64; off <<= 1) {
    s += __shfl_xor(s, off);
    ss += __shfl_xor(ss, off);
  }
  const float mu = s * (1.f / 512.f);
  const float rstd = rsqrtf(ss * (1.f / 512.f) - mu * mu + 1e-5f);
  bf16x8 o;
#pragma unroll
  for (int k = 0; k < 8; ++k) {
    int ch = lane * 8 + k;
    o[k] = (bf16)((v[k] - mu) * rstd * g[ch] + bb[ch]);
  }
  *(bf16x8*)&hcs[(size_t)row * 512 + lane * 8] = o;
}

// ---------------------------------------------------------------------------
// Kernel 4: FC GEMM (M=8192, N=2048, K=512). 128x256 tile, 8 waves, 3-deep
// counted-vmcnt pipeline (L=3). GELU epilogue via padded LDS overlay.
// ---------------------------------------------------------------------------
__global__ __launch_bounds__(512)
void gemm_fc_k(const bf16* __restrict__ A, const bf16* __restrict__ Bt,
               const float* __restrict__ bias, bf16* __restrict__ fo)
{
  const int K = 512;
  __shared__ __align__(16) char smem[73728]; // 72 KB
  bf16* As = (bf16*)smem;            // [3][4096] = 24 KB
  bf16* Bs = (bf16*)(smem + 24576);  // [3][8192] = 48 KB
  bf16* OT = (bf16*)smem;            // [128][264] overlay (post-loop)
  const int tid = threadIdx.x;
  const int wid = tid >> 6, lane = tid & 63;
  const int wr = wid >> 2, wcc = wid & 3;
  const int ml = lane & 15, kg = (lane >> 4) << 3;
  const int bid = blockIdx.x;
  const int xcd = bid & 7, chunk = bid >> 3;
  const int m0 = (xcd * 8 + (chunk & 7)) * 128;
  const int n0 = (chunk >> 3) * 256;

  const int rA = (wid << 4) + (lane >> 2), cA = (lane & 3) << 3;
  const bf16* Ag = A + (size_t)m0 * K;
  const bf16* Bg = Bt + (size_t)n0 * K;

  f32x4 acc[4][4] = {};

#define FC_STAGE(kk, bu)                                                      \
  do {                                                                        \
    gload_lds16(Ag + (size_t)rA * K + (kk) + cA,         As + (bu) * 4096 + wid * 512); \
    gload_lds16(Bg + (size_t)rA * K + (kk) + cA,         Bs + (bu) * 8192 + wid * 512); \
    gload_lds16(Bg + (size_t)(rA + 128) * K + (kk) + cA, Bs + (bu) * 8192 + 4096 + wid * 512); \
  } while (0)

  FC_STAGE(0, 0);
  FC_STAGE(32, 1);

  for (int kt = 0; kt < 16; ++kt) {
    if (kt == 15) VM_FENCE(0); else VM_FENCE(3);
    if (kt + 2 < 16) FC_STAGE((kt + 2) * 32, (kt + 2) % 3);
    const int cur = kt % 3;
    bf16x8 af[4], bfr[4];
#pragma unroll
    for (int mf = 0; mf < 4; ++mf)
      af[mf] = *(const bf16x8*)&As[cur * 4096 + (wr * 64 + mf * 16 + ml) * 32 + kg];
#pragma unroll
    for (int nf = 0; nf < 4; ++nf)
      bfr[nf] = *(const bf16x8*)&Bs[cur * 8192 + (wcc * 64 + nf * 16 + ml) * 32 + kg];
#pragma unroll
    for (int mf = 0; mf < 4; ++mf)
#pragma unroll
      for (int nf = 0; nf < 4; ++nf)
        acc[mf][nf] = __builtin_amdgcn_mfma_f32_16x16x32_bf16(
            af[mf], bfr[nf], acc[mf][nf], 0, 0, 0);
  }
#undef FC_STAGE

  __syncthreads();
  const int jrow0 = (lane >> 4) << 2;
#pragma unroll
  for (int nf = 0; nf < 4; ++nf) {
    const float bv = bias[n0 + wcc * 64 + nf * 16 + ml];
#pragma unroll
    for (int mf = 0; mf < 4; ++mf)
#pragma unroll
      for (int j = 0; j < 4; ++j) {
        float x = acc[mf][nf][j] + bv;
        float u = 0.7978845608f * (x + 0.044715f * x * x * x);
        float e = __expf(2.f * u);
        float th = 1.f - 2.f / (e + 1.f);
        OT[(wr * 64 + mf * 16 + jrow0 + j) * 264 + wcc * 64 + nf * 16 + ml] =
            (bf16)(0.5f * x * (1.f + th));
      }
  }
  __syncthreads();
#pragma unroll
  for (int it = 0; it < 8; ++it) {
    const int idx = it * 512 + tid;
    const int cg = idx & 31, r = idx >> 5;
    *(bf16x8*)&fo[(size_t)(m0 + r) * 2048 + n0 + cg * 8] =
        *(const bf16x8*)&OT[r * 264 + cg * 8];
  }
}

// ---------------------------------------------------------------------------
// Kernel 4b: split-K GEMM for N=512 stages (O, PR). BM=64, BN=128, grid 512,
// 3-deep counted-vmcnt pipeline. R17: epilogue stores restaged through LDS —
// O: bf16 [64][132] tile -> 256B row stores; PR: f32 [128][65] tile -> 256B
// tl-runs into the [v,b,c,h,w] output.
// ---------------------------------------------------------------------------
enum { EPI_O = 2, EPI_PR = 4 };

template <int EPI>
__global__ __launch_bounds__(512)
void gemmsk_k(const bf16* __restrict__ A, const bf16* __restrict__ Bt,
              const float* __restrict__ bias, const bf16* res,
              void* out0, int K)
{
  __shared__ __align__(16) char smem[73728]; // 72 KB
  bf16*  AS = (bf16*)smem;            // [3][2 half][2048] = 24 KB
  bf16*  BS = (bf16*)(smem + 24576);  // [3][2 half][4096] = 48 KB
  float* CF = (float*)smem;           // f32[64][128] = 32 KB overlay @0
  bf16*  OTb = (bf16*)(smem + 32768); // O: bf16[64][132] = 16.9 KB
  float* OTF = (float*)(smem + 32768);// PR: f32[128][65] = 33.3 KB

  const int tid = threadIdx.x;
  const int wid = tid >> 6, lane = tid & 63;
  const int half = wid >> 2, w2 = wid & 3;
  const int wr = w2 >> 1, wc = w2 & 1;
  const int ml = lane & 15, kg = (lane >> 4) << 3;
  const int bid = blockIdx.x;
  const int xcd = bid & 7, chunk = bid >> 3;
  const int m0 = (xcd * 16 + (chunk & 15)) * 64;
  const int n0 = (chunk >> 4) * 128;
  const int Kh = K >> 1;
  const int NK = Kh >> 5;

  const int eA = w2 * 512 + lane * 8;
  const int rA = eA >> 5, cA = eA & 31;
  const int eB0 = (w2 * 2) * 512 + lane * 8;
  const int rB0 = eB0 >> 5, cB0 = eB0 & 31;
  const int eB1 = eB0 + 512;
  const int rB1 = eB1 >> 5, cB1 = eB1 & 31;

  const bf16* Ag = A + (size_t)m0 * K + half * Kh;
  const bf16* Bg = Bt + (size_t)n0 * K + half * Kh;

  f32x4 acc[2][4] = {};

#define SK_STAGE(kk, bu)                                                      \
  do {                                                                        \
    gload_lds16(Ag + (size_t)rA * K + (kk) + cA,   AS + (bu) * 4096 + half * 2048 + w2 * 512); \
    gload_lds16(Bg + (size_t)rB0 * K + (kk) + cB0, BS + (bu) * 8192 + half * 4096 + (w2 * 2) * 512); \
    gload_lds16(Bg + (size_t)rB1 * K + (kk) + cB1, BS + (bu) * 8192 + half * 4096 + (w2 * 2 + 1) * 512); \
  } while (0)

  SK_STAGE(0, 0);
  SK_STAGE(32, 1);

  for (int kt = 0; kt < NK; ++kt) {
    if (kt == NK - 1) VM_FENCE(0); else VM_FENCE(3);
    if (kt + 2 < NK) SK_STAGE((kt + 2) * 32, (kt + 2) % 3);
    const int cur = kt % 3;
    const bf16* Ac = AS + cur * 4096 + half * 2048;
    const bf16* Bc = BS + cur * 8192 + half * 4096;
    bf16x8 af[2], bfr[4];
#pragma unroll
    for (int mf = 0; mf < 2; ++mf)
      af[mf] = *(const bf16x8*)&Ac[(wr * 32 + mf * 16 + ml) * 32 + kg];
#pragma unroll
    for (int nf = 0; nf < 4; ++nf)
      bfr[nf] = *(const bf16x8*)&Bc[(wc * 64 + nf * 16 + ml) * 32 + kg];
#pragma unroll
    for (int mf = 0; mf < 2; ++mf)
#pragma unroll
      for (int nf = 0; nf < 4; ++nf)
        acc[mf][nf] = __builtin_amdgcn_mfma_f32_16x16x32_bf16(
            af[mf], bfr[nf], acc[mf][nf], 0, 0, 0);
  }
#undef SK_STAGE

  const int jrow0 = (lane >> 4) << 2;
  __syncthreads(); // staging dead; CF/OT may overlay
  if (half == 0) {
#pragma unroll
    for (int mf = 0; mf < 2; ++mf)
#pragma unroll
      for (int nf = 0; nf < 4; ++nf)
#pragma unroll
        for (int j = 0; j < 4; ++j)
          CF[(wr * 32 + mf * 16 + jrow0 + j) * 128 + wc * 64 + nf * 16 + ml] =
              acc[mf][nf][j];
  }
  __syncthreads();
  if (half == 1) {
#pragma unroll
    for (int nf = 0; nf < 4; ++nf) {
      const int n = n0 + wc * 64 + nf * 16 + ml;
      const int nl = wc * 64 + nf * 16 + ml;
      const float bv = bias[n];
#pragma unroll
      for (int mf = 0; mf < 2; ++mf) {
        const int mbase = m0 + wr * 32 + mf * 16 + jrow0;
        const int mloc = wr * 32 + mf * 16 + jrow0;
        float v4[4];
#pragma unroll
        for (int j = 0; j < 4; ++j)
          v4[j] = acc[mf][nf][j] +
                  CF[(mloc + j) * 128 + nl];
        if constexpr (EPI == EPI_O) {
#pragma unroll
          for (int j = 0; j < 4; ++j) {
            const size_t idx = (size_t)(mbase + j) * 512 + n;
            OTb[(mloc + j) * 132 + nl] = (bf16)(v4[j] + bv + (float)res[idx]);
          }
        } else { // EPI_PR: f32 tile [n][tl]
#pragma unroll
          for (int j = 0; j < 4; ++j)
            OTF[nl * 65 + mloc + j] =
                v4[j] + bv + (float)res[(size_t)(mbase + j) * 512 + n];
        }
      }
    }
  }
  __syncthreads();
  if constexpr (EPI == EPI_O) {
    bf16* cs = (bf16*)out0;
#pragma unroll
    for (int it = 0; it < 2; ++it) {
      const int u2 = it * 512 + tid;
      const int c8 = u2 & 15, r = u2 >> 4;
      *(bf16x8*)&cs[(size_t)(m0 + r) * 512 + n0 + c8 * 8] =
          *(const bf16x8*)&OTb[r * 132 + c8 * 8];
    }
  } else {
    float* out = (float*)out0;
    const int b = m0 >> 10, t00 = m0 & 1023;
    const int v = t00 >> 8, tl0 = t00 & 255;
#pragma unroll
    for (int it = 0; it < 4; ++it) {
      const int u2 = it * 512 + tid;
      const int tlc = u2 & 15, nl = u2 >> 4;
      *(f32x4*)&out[(((size_t)v * 8 + b) * 512 + n0 + nl) * 256 + tl0 + tlc * 4] =
          *(const f32x4*)&OTF[nl * 65 + tlc * 4];
    }
  }
}

// ---------------------------------------------------------------------------
// Kernel 4c: merged Q + KV projection GEMM, 3-deep counted-vmcnt (L=4),
// LDS-staged stores. Grid 768, xcd == b.
// ---------------------------------------------------------------------------
__global__ __launch_bounds__(256)
void gemm_qkv_k(const bf16* __restrict__ Aq, const bf16* __restrict__ Akv,
                const bf16* __restrict__ WqT, const bf16* __restrict__ WkvT,
                const float* __restrict__ bq, const float* __restrict__ bkv,
                bf16* __restrict__ q_buf, bf16* __restrict__ k_buf,
                bf16* __restrict__ v_t)
{
  const int K = 512;
  __shared__ __align__(16) char smem[49152]; // 48 KB
  bf16* As = (bf16*)smem;            // [3][4096] = 24 KB
  bf16* Bs = (bf16*)(smem + 24576);  // [3][4096] = 24 KB
  const int tid = threadIdx.x;
  const int wid = tid >> 6, lane = tid & 63;
  const int wr = wid >> 1, wc = wid & 1;
  const int ml = lane & 15, kg = (lane >> 4) << 3;
  const int bid = blockIdx.x;
  const int xcd = bid & 7, chunk = bid >> 3;
  const int m0 = (xcd * 8 + (chunk & 7)) * 128;
  const int ybl = chunk >> 3;
  const bool isq = ybl < 4;
  const bf16* A     = isq ? Aq  : Akv;
  const bf16* Bt    = isq ? WqT : WkvT;
  const float* bias = isq ? bq : bkv;
  const int n0 = isq ? (ybl << 7) : ((ybl - 4) << 7);

  const int e0 = wid * 512 + lane * 8;
  const int r0 = e0 >> 5, c0 = e0 & 31;
  const int e1 = e0 + 2048;
  const int r1 = e1 >> 5, c1 = e1 & 31;

  const bf16* Ag = A + (size_t)m0 * K;
  const bf16* Bg = Bt + (size_t)n0 * K;

  f32x4 acc[4][4] = {};

#define QKV_STAGE(kk, bu)                                                     \
  do {                                                                        \
    gload_lds16(Ag + (size_t)r0 * K + (kk) + c0, As + (bu) * 4096 + wid * 512); \
    gload_lds16(Ag + (size_t)r1 * K + (kk) + c1, As + (bu) * 4096 + 2048 + wid * 512); \
    gload_lds16(Bg + (size_t)r0 * K + (kk) + c0, Bs + (bu) * 4096 + wid * 512); \
    gload_lds16(Bg + (size_t)r1 * K + (kk) + c1, Bs + (bu) * 4096 + 2048 + wid * 512); \
  } while (0)

  QKV_STAGE(0, 0);
  QKV_STAGE(32, 1);

  for (int kt = 0; kt < 16; ++kt) {
    if (kt == 15) VM_FENCE(0); else VM_FENCE(4);
    if (kt + 2 < 16) QKV_STAGE((kt + 2) * 32, (kt + 2) % 3);
    const int cur = kt % 3;
    bf16x8 af[4], bfr[4];
#pragma unroll
    for (int mf = 0; mf < 4; ++mf)
      af[mf] = *(const bf16x8*)&As[cur * 4096 + (wr * 64 + mf * 16 + ml) * 32 + kg];
#pragma unroll
    for (int nf = 0; nf < 4; ++nf)
      bfr[nf] = *(const bf16x8*)&Bs[cur * 4096 + (wc * 64 + nf * 16 + ml) * 32 + kg];
#pragma unroll
    for (int mf = 0; mf < 4; ++mf)
#pragma unroll
      for (int nf = 0; nf < 4; ++nf)
        acc[mf][nf] = __builtin_amdgcn_mfma_f32_16x16x32_bf16(
            af[mf], bfr[nf], acc[mf][nf], 0, 0, 0);
  }
#undef QKV_STAGE

  __syncthreads();
  bf16* OT = (bf16*)smem; // [128][132] padded overlay
  const int jrow0 = (lane >> 4) << 2;
  const int b = m0 >> 10, t0 = m0 & 1023;
  if (ybl < 8) { // Q or K: stage row-major (row=m, col=n)
#pragma unroll
    for (int nf = 0; nf < 4; ++nf) {
      const float bv = bias[n0 + wc * 64 + nf * 16 + ml];
#pragma unroll
      for (int mf = 0; mf < 4; ++mf)
#pragma unroll
        for (int j = 0; j < 4; ++j)
          OT[(wr * 64 + mf * 16 + jrow0 + j) * 132 + wc * 64 + nf * 16 + ml] =
              (bf16)(acc[mf][nf][j] + bv);
    }
    __syncthreads();
    bf16* dst = isq ? q_buf : k_buf;
    const int h0 = n0 >> 6;
#pragma unroll
    for (int it = 0; it < 8; ++it) {
      const int idx = it * 256 + tid;
      const int dg = idx & 7, r = (idx >> 3) & 127, hl = idx >> 10;
      *(bf16x8*)&dst[(((size_t)b * 8 + h0 + hl) * 1024 + t0 + r) * 64 + dg * 8] =
          *(const bf16x8*)&OT[r * 132 + hl * 64 + dg * 8];
    }
  } else { // V: stage col-major for t-contiguous stores
#pragma unroll
    for (int nf = 0; nf < 4; ++nf) {
      const float bv = bias[n0 + wc * 64 + nf * 16 + ml];
#pragma unroll
      for (int mf = 0; mf < 4; ++mf) {
        bf16x4 o;
#pragma unroll
        for (int j = 0; j < 4; ++j) o[j] = (bf16)(acc[mf][nf][j] + bv);
        *(bf16x4*)&OT[(wc * 64 + nf * 16 + ml) * 132 + wr * 64 + mf * 16 + jrow0] = o;
      }
    }
    __syncthreads();
    const int h0 = (n0 - 512) >> 6;
#pragma unroll
    for (int it = 0; it < 8; ++it) {
      const int idx = it * 256 + tid;
      const int og = idx & 15, c = idx >> 4;
      const int hl = c >> 6, d = c & 63;
      *(bf16x8*)&v_t[(((size_t)b * 8 + h0 + hl) * 64 + d) * 1024 + t0 + og * 8] =
          *(const bf16x8*)&OT[c * 132 + og * 8];
    }
  }
}

// ---------------------------------------------------------------------------
// Kernel 5: block-causal flash attention, QBLK=128 (8 waves, 512 threads),
// 2-buffer syncthreads pipeline (R15 form) + y restaged via P buffer.
// ---------------------------------------------------------------------------
__global__ __launch_bounds__(512)
void attn_k(const bf16* __restrict__ qb, const bf16* __restrict__ kb,
            const bf16* __restrict__ vt, bf16* __restrict__ y)
{
  __shared__ bf16 Ks[2][4096];
  __shared__ bf16 Vs[2][4096];
  __shared__ bf16 Ps[8][1024];
  const int tid = threadIdx.x, wid = tid >> 6, lane = tid & 63;
  const int L = blockIdx.x;                  // 0..511
  const int xcd = L & 7, chunk = L >> 3;     // chunk 0..63
  const int bh = (xcd << 3) + (chunk >> 3);  // b == xcd
  const int qt = 7 - (chunk & 7);            // long blocks first
  const int b = bh >> 3, h = bh & 7;
  const int t0 = qt << 7;
  const int ml = lane & 15, hi = lane >> 4, kg = hi << 3;

  const bf16* qrow = qb + ((size_t)bh * 1024 + t0 + wid * 16) * 64;
  bf16x8 aq[2];
  aq[0] = *(const bf16x8*)&qrow[ml * 64 + kg];
  aq[1] = *(const bf16x8*)&qrow[ml * 64 + 32 + kg];

  f32x4 accO[4] = {};
  float lsum[4] = {0.f, 0.f, 0.f, 0.f};

  const int nkt = ((qt >> 1) + 1) << 2;      // 4..16 tiles of 64 tokens
  const bf16* kbase = kb + (size_t)bh * 1024 * 64;
  const bf16* vbase = vt + (size_t)bh * 64 * 1024;

  const int sr = tid >> 3;                       // 0..63
  const int sg = ((tid & 7) ^ (sr & 7)) << 3;    // swizzled granule (elems)
  bf16* pw = &Ps[wid][0];

  gload_lds16(kbase + (size_t)sr * 64 + sg,   &Ks[0][wid * 512]);
  gload_lds16(vbase + (size_t)sr * 1024 + sg, &Vs[0][wid * 512]);

  int cur = 0;
  for (int kt = 0; kt < nkt; ++kt) {
    __syncthreads();
    if (kt + 1 < nkt) {
      const int tk0 = (kt + 1) << 6;
      const int nb = cur ^ 1;
      gload_lds16(kbase + (size_t)(tk0 + sr) * 64 + sg,   &Ks[nb][wid * 512]);
      gload_lds16(vbase + (size_t)sr * 1024 + tk0 + sg,   &Vs[nb][wid * 512]);
    }

    f32x4 sa[4] = {};
    __builtin_amdgcn_s_setprio(1);
#pragma unroll
    for (int nf = 0; nf < 4; ++nf) {
      const int row = nf * 16 + ml;
#pragma unroll
      for (int ks = 0; ks < 2; ++ks) {
        const int g = ((ks * 4 + hi) ^ (ml & 7)) << 3;
        bf16x8 bk = *(const bf16x8*)&Ks[cur][row * 64 + g];
        sa[nf] = __builtin_amdgcn_mfma_f32_16x16x32_bf16(aq[ks], bk, sa[nf], 0, 0, 0);
      }
    }
    __builtin_amdgcn_s_setprio(0);

#pragma unroll
    for (int nf = 0; nf < 4; ++nf) {
      const int gp0 = nf * 2 + (ml >> 3);
#pragma unroll
      for (int j = 0; j < 4; ++j) {
        const float p = __expf(sa[nf][j] * 0.125f);
        lsum[j] += p;
        const int prow = (hi << 2) + j;
        pw[prow * 64 + ((gp0 ^ (prow & 7)) << 3) + (ml & 7)] = (bf16)p;
      }
    }

    __builtin_amdgcn_s_setprio(1);
#pragma unroll
    for (int ks = 0; ks < 2; ++ks) {
      const int g = ((ks * 4 + hi) ^ (ml & 7)) << 3;
      bf16x8 pa = *(const bf16x8*)&pw[ml * 64 + g];
#pragma unroll
      for (int df = 0; df < 4; ++df) {
        bf16x8 bv = *(const bf16x8*)&Vs[cur][(df * 16 + ml) * 64 + g];
        accO[df] = __builtin_amdgcn_mfma_f32_16x16x32_bf16(pa, bv, accO[df], 0, 0, 0);
      }
    }
    __builtin_amdgcn_s_setprio(0);
    cur ^= 1;
  }

  float inv[4];
#pragma unroll
  for (int j = 0; j < 4; ++j) {
    float s = lsum[j];
#pragma unroll
    for (int off = 1; off < 16; off <<= 1) s += __shfl_xor(s, off);
    inv[j] = 1.f / s;
  }
  // restage y through the (now-free) per-wave P buffer: [16 t][64 c] bf16
#pragma unroll
  for (int df = 0; df < 4; ++df)
#pragma unroll
    for (int j = 0; j < 4; ++j)
      pw[((hi << 2) + j) * 64 + df * 16 + ml] = (bf16)(accO[df][j] * inv[j]);
  // wave-internal lgkm ordering covers write->read; stream 128B rows
#pragma unroll
  for (int it = 0; it < 2; ++it) {
    const int u2 = it * 64 + lane;
    const int c8 = u2 & 7, r = u2 >> 3;
    *(bf16x8*)&y[((size_t)b * 1024 + t0 + wid * 16 + r) * 512 + h * 64 + c8 * 8] =
        *(const bf16x8*)&pw[r * 64 + c8 * 8];
  }
}

// ---------------------------------------------------------------------------
extern "C" void kernel_launch(void* const* d_in, const int* in_sizes, int n_in,
                              void* d_out, int out_size, void* d_ws, size_t ws_size,
                              hipStream_t stream)
{
  const float* xi    = (const float*)d_in[0];
  const float* xc    = (const float*)d_in[1];
  const float* xj    = (const float*)d_in[2];
  const float* ln1_g = (const float*)d_in[3];
  const float* ln1_b = (const float*)d_in[4];
  const float* ln2_g = (const float*)d_in[5];
  const float* ln2_b = (const float*)d_in[6];
  const float* Wq    = (const float*)d_in[7];
  const float* bq    = (const float*)d_in[8];
  const float* Wkv   = (const float*)d_in[9];
  const float* bkv   = (const float*)d_in[10];
  const float* Wo    = (const float*)d_in[11];
  const float* bo    = (const float*)d_in[12];
  const float* Wfc   = (const float*)d_in[13];
  const float* bfc   = (const float*)d_in[14];
  const float* Wpr   = (const float*)d_in[15];
  const float* bpr   = (const float*)d_in[16];

  char* ws = (char*)d_ws;
  const size_t MB = 1ull << 20;
  bf16*  qs    = (bf16*)(ws + 0);                  // 8 MB
  bf16*  kvs   = (bf16*)(ws + 8 * MB);             // 8 MB
  bf16*  csb   = (bf16*)(ws + 16 * MB);            // 8 MB (bf16 residual)
  bf16*  WqT   = (bf16*)(ws + 32 * MB);
  bf16*  WkvT  = (bf16*)(ws + 32 * MB + 512 * 1024);
  bf16*  WoT   = (bf16*)(ws + 33 * MB + 512 * 1024);
  bf16*  WfcT  = (bf16*)(ws + 34 * MB);
  bf16*  WprT  = (bf16*)(ws + 36 * MB);
  bf16*  q_buf = (bf16*)(ws + 38 * MB);
  bf16*  k_buf = (bf16*)(ws + 46 * MB);
  bf16*  v_t   = (bf16*)(ws + 54 * MB);
  bf16*  yb    = (bf16*)(ws + 0);                  // reuse qs
  bf16*  hcs   = (bf16*)(ws + 8 * MB);             // reuse kvs
  bf16*  fcact = (bf16*)(ws + 38 * MB);            // reuse q/k/v

  prep_k<<<dim3(1536), 256, 0, stream>>>(Wq, Wkv, Wo, Wfc, Wpr,
                                         WqT, WkvT, WoT, WfcT, WprT,
                                         xi, xj, xc, ln1_g, ln1_b, qs, kvs, csb);

  gemm_qkv_k<<<dim3(768), 256, 0, stream>>>(qs, kvs, WqT, WkvT, bq, bkv,
                                            q_buf, k_buf, v_t);

  attn_k<<<dim3(512), 512, 0, stream>>>(q_buf, k_buf, v_t, yb);

  gemmsk_k<EPI_O><<<dim3(512), 512, 0, stream>>>(yb, WoT, bo, csb,
                                                 (void*)csb, 512);

  ln2_k<<<dim3(2048), 256, 0, stream>>>(csb, ln2_g, ln2_b, hcs);

  gemm_fc_k<<<dim3(512), 512, 0, stream>>>(hcs, WfcT, bfc, fcact);

  gemmsk_k<EPI_PR><<<dim3(512), 512, 0, stream>>>(fcact, WprT, bpr, csb,
                                                  d_out, 2048);

  (void)in_sizes; (void)n_in; (void)out_size; (void)ws_size;
}